// Round 15
// baseline (216.090 us; speedup 1.0000x reference)
//
#include <hip/hip_runtime.h>
#include <hip/hip_bf16.h>
#include <stdint.h>

#define NPTS 131072
#define DIM  512
#define KC   512
#define BM   32
#define BK   32
#define NKT  16          // DIM / BK

typedef float f32x16 __attribute__((ext_vector_type(16)));
typedef float f32x4  __attribute__((ext_vector_type(4)));
typedef short bf16x8 __attribute__((ext_vector_type(8)));

__device__ __forceinline__ float sq4(f32x4 a) {
  return a.x*a.x + a.y*a.y + a.z*a.z + a.w*a.w;
}

// packed RNE fp32->bf16 (v_cvt_pk_bf16_f32)
__device__ __forceinline__ bf16x8 pack8c(f32x4 a, f32x4 b) {
  union { __hip_bfloat162 h; short s[2]; } u0, u1, u2, u3;
  u0.h = __float22bfloat162_rn(make_float2(a.x, a.y));
  u1.h = __float22bfloat162_rn(make_float2(a.z, a.w));
  u2.h = __float22bfloat162_rn(make_float2(b.x, b.y));
  u3.h = __float22bfloat162_rn(make_float2(b.z, b.w));
  bf16x8 r;
  r[0] = u0.s[0]; r[1] = u0.s[1]; r[2] = u1.s[0]; r[3] = u1.s[1];
  r[4] = u2.s[0]; r[5] = u2.s[1]; r[6] = u3.s[0]; r[7] = u3.s[1];
  return r;
}

// scalar RNE (cluster pre-kernel only)
__device__ __forceinline__ short f2bf(float f) {
  union { float f; unsigned u; } v; v.f = f;
  unsigned r = v.u + 0x7FFFu + ((v.u >> 16) & 1u);
  return (short)(r >> 16);
}
__device__ __forceinline__ bf16x8 pack8(f32x4 a, f32x4 b) {
  bf16x8 p;
  p[0] = f2bf(a.x); p[1] = f2bf(a.y); p[2] = f2bf(a.z); p[3] = f2bf(a.w);
  p[4] = f2bf(b.x); p[5] = f2bf(b.y); p[6] = f2bf(b.z); p[7] = f2bf(b.w);
  return p;
}

__device__ __forceinline__ void gload_lds16(const void* g, void* l) {
  __builtin_amdgcn_global_load_lds(
      (const __attribute__((address_space(1))) unsigned int*)g,
      (__attribute__((address_space(3))) unsigned int*)l, 16, 0, 0);
}

// ---------------------------------------------------------------------------
// Cluster pre-kernel (layout verified R5-R14, unchanged): fp32 [512][512] ->
// bf16 in MFMA-B-fragment order. Short offset = q*8192 + wn*2048 + nt*512 +
// (h*32+r)*8 where q = k/16. The main kernel loads fragments DIRECTLY TO
// REGISTERS: per (q,wn,nt) a wave reads 64 lanes x 16 B = contiguous 1 KB
// (16 fully-used sectors), L2-resident (512 KB total).
// c2[n] = ||c_n||^2 fp32.
// ---------------------------------------------------------------------------
__global__ void dec_pack(const float* __restrict__ C, short* __restrict__ Bp,
                         float* __restrict__ c2) {
  const int n    = blockIdx.x;
  const int lane = threadIdx.x;
  const float* src = C + (size_t)n * DIM + lane * 8;
  f32x4 v0 = *(const f32x4*)src;
  f32x4 v1 = *(const f32x4*)(src + 4);
  float s = sq4(v0) + sq4(v1);
  #pragma unroll
  for (int m = 1; m < 64; m <<= 1) s += __shfl_xor(s, m, 64);
  if (lane == 0) c2[n] = s;
  const int kt = lane >> 2;
  const int st = (lane >> 1) & 1;
  const int hh = lane & 1;
  const int wn = n >> 7, nt = (n >> 5) & 3, r = n & 31;
  const size_t slot =
      (((size_t)(kt * 2 + st) * 4 + wn) * 4 + nt) * 64 + hh * 32 + r;
  *(bf16x8*)(Bp + slot * 8) = pack8(v0, v1);
}

// ---------------------------------------------------------------------------
// Main fused kernel (R15): B direct-to-registers, A-only LDS staging,
// 3 blocks/CU.
// 256 threads = 4 waves (wn = wave); block tile 32 x 512 (full cluster
// width -> block-local normalization). Wave tile 32 x 128:
// 8 x mfma_f32_32x32x16_bf16 per kt (BK=32), acc = 4 x f32x16 (64 AGPR).
//
// B path: NO LDS. Per kt per wave: 8 fragment loads straight from the
//   pre-packed L2-resident Bp (contiguous 1 KB each), ping-pong prefetched
//   ONE FULL PHASE ahead (fixes R9-main2's same-iteration consume). The
//   compiler inserts exact per-use counted vmcnt for the register loads.
// A path: gload_lds staging (lane*16 contract: thread t -> row t>>3, dest
//   linear t*16B, source chunk (t&7)^(row&7)), dbuf 2 x 4 KB.
// Phase kt: [vmcnt(8): A(kt) landed, B(kt) 8 ops stay in flight]
//   [s_barrier] [stage A(kt+1) 1 op; load B(kt+1) 8 ops]
//   [compute kt: 4x A-frag ds_read_b128 (XOR-swizzled) -> cvt_pk; 8 MFMA
//    with B(kt) regs; x2 fused from fp32 regs].
// LDS ~8.8 KB/block; ~160 unified regs, __launch_bounds__(256,3) ->
// 3 blocks/CU = 3 independent barrier domains (vs 2 in R11/R13).
// Full unroll keeps the bqA/bqB ping-pong statically indexed (rule #20).
// ---------------------------------------------------------------------------
__global__ __launch_bounds__(256, 3)
void dec_main(const float* __restrict__ X, const short* __restrict__ Bp,
              const float* __restrict__ c2g, float* __restrict__ out) {
  __shared__ float Ab[2][1024];     // 2 x 4 KB fp32 A tiles (chunk-swizzled)
  __shared__ float part[4][BM];
  __shared__ float rowinv[BM];

  const int tid  = threadIdx.x;
  const int lane = tid & 63;
  const int wn   = tid >> 6;    // 0..3 : column quarter (one wave each)
  const int l31  = lane & 31;
  const int h    = lane >> 5;
  const int row0 = blockIdx.x * BM;

  // A staging (lane*16 contract): thread t -> row t>>3, dest chunk t&7 at
  // linear t*16B; source chunk = (t&7) ^ (row&7).
  const float* asrc = X + (size_t)(row0 + (tid >> 3)) * DIM +
                      (((tid & 7) ^ ((tid >> 3) & 7)) << 2);
  // B fragment base (shorts): + (kt*2+s)*8192 + nt*512
  const short* bB = Bp + wn * 2048 + lane * 8;

  const int asw = l31 & 7;      // read-side chunk XOR

  f32x16 acc[4];
  #pragma unroll
  for (int nt = 0; nt < 4; ++nt) acc[nt] = (f32x16)0.f;
  float x2 = 0.f;

  bf16x8 bqA[2][4], bqB[2][4];  // named ping-pong B fragment sets

  // ---- prologue: stage A(0) [1 op], load B(0) -> bqA [8 ops] ----
  gload_lds16(asrc, &Ab[0][tid * 4]);
  #pragma unroll
  for (int s = 0; s < 2; ++s)
    #pragma unroll
    for (int nt = 0; nt < 4; ++nt)
      bqA[s][nt] = *(const bf16x8*)(bB + s * 8192 + nt * 512);
  __builtin_amdgcn_sched_barrier(0);

  // ---- K loop: 16 phases, fully unrolled (static ping-pong indices) ----
  #pragma unroll
  for (int kt = 0; kt < NKT; ++kt) {
    // A(kt) landed (9 outstanding: A(kt) oldest, then B(kt) x8 -> keep 8)
    asm volatile("s_waitcnt vmcnt(8)" ::: "memory");
    __builtin_amdgcn_sched_barrier(0);
    __builtin_amdgcn_s_barrier();
    __builtin_amdgcn_sched_barrier(0);
    {
      const int ka = (kt + 1 < NKT) ? kt + 1 : NKT - 1;   // clamped (dead ok)
      gload_lds16(asrc + ka * BK, &Ab[(kt + 1) & 1][tid * 4]);
      #pragma unroll
      for (int s = 0; s < 2; ++s)
        #pragma unroll
        for (int nt = 0; nt < 4; ++nt) {
          bf16x8 v = *(const bf16x8*)(bB + (size_t)(ka * 2 + s) * 8192 +
                                      nt * 512);
          if (kt & 1) bqA[s][nt] = v; else bqB[s][nt] = v;
        }
    }
    __builtin_amdgcn_sched_barrier(0);
    {
      const float* A = &Ab[kt & 1][0];
      #pragma unroll
      for (int s = 0; s < 2; ++s) {
        f32x4 lo = *(const f32x4*)
            &A[l31 * 32 + (((s * 4 + h * 2 + 0) ^ asw) << 2)];
        f32x4 hi = *(const f32x4*)
            &A[l31 * 32 + (((s * 4 + h * 2 + 1) ^ asw) << 2)];
        x2 += sq4(lo) + sq4(hi);
        bf16x8 af = pack8c(lo, hi);
        #pragma unroll
        for (int nt = 0; nt < 4; ++nt) {
          bf16x8 bv = (kt & 1) ? bqB[s][nt] : bqA[s][nt];
          acc[nt] = __builtin_amdgcn_mfma_f32_32x32x16_bf16(
              af, bv, acc[nt], 0, 0, 0);
        }
      }
    }
  }

  // ---- x2: combine the two k-halves; lane l31 holds x2(row l31) ----
  x2 += __shfl_xor(x2, 32, 64);

  float c2v[4];
  #pragma unroll
  for (int nt = 0; nt < 4; ++nt) c2v[nt] = c2g[wn * 128 + nt * 32 + l31];

  // ---- q = rcp(1+d2), per-row partial sums over this wave's 128 cols ----
  float srow[16];
  #pragma unroll
  for (int r = 0; r < 16; ++r) {
    const int mloc = (r & 3) + 8 * (r >> 2) + 4 * h;   // 0..31
    const float x2m = __shfl(x2, mloc, 64);
    float s = 0.f;
    #pragma unroll
    for (int nt = 0; nt < 4; ++nt) {
      float d2 = fmaxf(x2m + c2v[nt] - 2.f * acc[nt][r], 0.f);
      float q = __builtin_amdgcn_rcpf(1.f + d2);
      acc[nt][r] = q;
      s += q;
    }
    #pragma unroll
    for (int msk = 1; msk < 32; msk <<= 1) s += __shfl_xor(s, msk, 64);
    srow[r] = s;
  }

  if (l31 == 0) {
    #pragma unroll
    for (int r = 0; r < 16; ++r)
      part[wn][(r & 3) + 8 * (r >> 2) + 4 * h] = srow[r];
  }
  __syncthreads();
  if (tid < BM)
    rowinv[tid] = __builtin_amdgcn_rcpf(part[0][tid] + part[1][tid] +
                                        part[2][tid] + part[3][tid]);
  __syncthreads();

  // ---- normalize + coalesced stores ----
  #pragma unroll
  for (int r = 0; r < 16; ++r) {
    const int row = (r & 3) + 8 * (r >> 2) + 4 * h;
    const float iv = rowinv[row];
    float* o = out + (size_t)(row0 + row) * KC + wn * 128 + l31;
    #pragma unroll
    for (int nt = 0; nt < 4; ++nt)
      o[nt * 32] = acc[nt][r] * iv;
  }
}

extern "C" void kernel_launch(void* const* d_in, const int* in_sizes, int n_in,
                              void* d_out, int out_size, void* d_ws, size_t ws_size,
                              hipStream_t stream) {
  const float* X = (const float*)d_in[0];   // inputs  [131072, 512] fp32
  const float* C = (const float*)d_in[1];   // clusters [512, 512] fp32
  float* out = (float*)d_out;               // [131072, 512] fp32

  short* Bp = (short*)d_ws;                                   // 512 KB packed bf16 clusters
  float* c2 = (float*)((char*)d_ws + (size_t)KC * DIM * 2);   // 2 KB cluster norms

  dec_pack<<<KC, 64, 0, stream>>>(C, Bp, c2);
  dec_main<<<NPTS / BM, 256, 0, stream>>>(X, Bp, c2, out);
}